// Round 2
// baseline (1618.221 us; speedup 1.0000x reference)
//
#include <hip/hip_runtime.h>
#include <stdint.h>

// Problem constants (fixed shapes)
#define E_ 8
#define H_ 2048
#define I_ 4096
#define T_ 1024
#define K_ 2
#define GS_ 128
#define NPAIR (T_ * K_)   // 2048

// GEMM tile config
#define BM 128
#define BN 64
#define BK 64

// XOR-swizzled LDS: row stride 64 shorts (128 B), chunk = 8 shorts (16 B).
// chunk c of row r lives at short-offset CH(r,c); conflict-free b128 reads.
#define CH(r, c) ((((c) ^ ((r) & 7)) << 3))

typedef __attribute__((ext_vector_type(8))) short s16x8;    // raw 16B move
typedef _Float16 f16x2 __attribute__((ext_vector_type(2))); // packed half pair
typedef _Float16 f16x8 __attribute__((ext_vector_type(8))); // MFMA A/B frag
typedef __attribute__((ext_vector_type(4))) float f32x4;    // C/D frag

static __device__ __forceinline__ unsigned short f2h(float f) {
    _Float16 h = (_Float16)f;
    return __builtin_bit_cast(unsigned short, h);
}
static __device__ __forceinline__ uint32_t pkrtz(float lo, float hi) {
    return __builtin_bit_cast(uint32_t, __builtin_amdgcn_cvt_pkrtz(lo, hi));
}

// ---------------- x -> f16 pre-pass ----------------
__global__ void x2h_kernel(const float* __restrict__ x, unsigned short* __restrict__ xh) {
    int i = (blockIdx.x * 256 + threadIdx.x) * 8;
    float4 a = *(const float4*)(x + i);
    float4 b = *(const float4*)(x + i + 4);
    uint4 st = make_uint4(pkrtz(a.x, a.y), pkrtz(a.z, a.w),
                          pkrtz(b.x, b.y), pkrtz(b.z, b.w));
    *(uint4*)(xh + i) = st;
}

// ---------------- zero output ----------------
__global__ void zero_f4(float4* p, int n4) {
    int i = blockIdx.x * blockDim.x + threadIdx.x;
    if (i < n4) p[i] = make_float4(0.f, 0.f, 0.f, 0.f);
}

// ---------------- router: build expert-sorted pair list ----------------
__global__ void router_kernel(const int* __restrict__ ridx,
                              const float* __restrict__ rw,
                              int* __restrict__ seg,      // [E_+1]
                              int* __restrict__ ptok,     // [NPAIR]
                              float* __restrict__ pw)     // [NPAIR]
{
    __shared__ int cnt[E_];
    __shared__ int cur[E_];
    int tid = threadIdx.x;
    if (tid < E_) cnt[tid] = 0;
    __syncthreads();
    for (int p = tid; p < NPAIR; p += blockDim.x)
        atomicAdd(&cnt[ridx[p]], 1);
    __syncthreads();
    if (tid == 0) {
        int s = 0;
        for (int e = 0; e < E_; e++) { seg[e] = s; cur[e] = s; s += cnt[e]; }
        seg[E_] = s;
    }
    __syncthreads();
    for (int p = tid; p < NPAIR; p += blockDim.x) {
        int e = ridx[p];
        int pos = atomicAdd(&cur[e], 1);
        ptok[pos] = p >> 1;     // K_ == 2
        pw[pos] = rw[p];
    }
}

// dequant 4 packed bytes (int4 of int32s) -> 8 f16 (one 16B chunk).
// Magic trick: as_half(0x6400 | q) == 1024 + q exactly (q in [0,15]),
// so half2(1024+hi, 1024+lo) is 4 int ops; then (p-1024)*sc+zp in packed
// f16. Subtract 1024 BEFORE the fma: q and 1024+q are exact in f16, while
// folding -1024*sc into the zero point would round at ulp(21) ~ 0.016 and
// poison the weights.
static __device__ __forceinline__ void dq_chunk(int4 q, f16x2 sc, f16x2 zp,
                                                unsigned short* dst) {
    uint32_t r[4];
    int qa[4] = {q.x, q.y, q.z, q.w};
    const f16x2 k1024 = {(_Float16)1024.f, (_Float16)1024.f};
#pragma unroll
    for (int j = 0; j < 4; j++) {
        uint32_t b = (uint32_t)qa[j];          // one meaningful byte per int32
        uint32_t p = 0x64006400u | (b >> 4) | ((b & 0xfu) << 16);
        f16x2 ph = __builtin_bit_cast(f16x2, p);
        f16x2 w = (ph - k1024) * sc + zp;       // v_pk_add + v_pk_fma
        r[j] = __builtin_bit_cast(uint32_t, w);
    }
    *(uint4*)dst = make_uint4(r[0], r[1], r[2], r[3]);
}

// ---------------- GEMM1: h = gelu(x@Wg^T) * (x@Wu^T), f16 out ----------------
__global__ __launch_bounds__(256, 5) void gemm1_kernel(
    const unsigned short* __restrict__ xh,   // [T][H] f16
    const int* __restrict__ gu_packed,       // [E][2I][H/2] (one byte per int32)
    const float* __restrict__ gu_scales,     // [E][2I][H/GS]
    const float* __restrict__ gu_zeros,
    const int* __restrict__ seg,
    const int* __restrict__ ptok,
    unsigned short* __restrict__ h_act)      // [NPAIR][I_] f16 bits
{
    const int e = blockIdx.z;
    const int seg0 = seg[e], seg1 = seg[e + 1];
    const int m0 = blockIdx.y * BM;
    if (seg0 + m0 >= seg1) return;
    const int n0 = blockIdx.x * BN;

    __shared__ __align__(16) unsigned short sX[BM * 64];
    __shared__ __align__(16) unsigned short sG[BN * 64];
    __shared__ __align__(16) unsigned short sU[BN * 64];

    const int tid = threadIdx.x;
    const int lane = tid & 63;
    const int wave = tid >> 6;
    const int wm = (wave >> 1) * 64;   // wave tile 64(m) x 32(n)
    const int wn = (wave & 1) * 32;
    const int quad = lane >> 4;
    const int l16 = lane & 15;

    // X staging: 2 threads/row, 4 chunks (32 shorts) each
    const int xr = tid >> 1;
    const int xc0 = (tid & 1) * 4;
    int slotX = seg0 + m0 + xr;
    if (slotX > NPAIR - 1) slotX = NPAIR - 1;
    const unsigned short* xrow = xh + (size_t)ptok[slotX] * H_ + xc0 * 8;

    // weight staging: 4 threads/row, 8 ints (2 chunks) each
    const int wr = tid >> 2;
    const int wc0 = (tid & 3) * 2;
    const int ng = n0 + wr;
    const int nu = n0 + I_ + wr;
    const int* gprow = gu_packed + ((size_t)e * (2 * I_) + ng) * (H_ / 2) + (tid & 3) * 8;
    const int* uprow = gu_packed + ((size_t)e * (2 * I_) + nu) * (H_ / 2) + (tid & 3) * 8;
    const float* gsrow = gu_scales + ((size_t)e * (2 * I_) + ng) * (H_ / GS_);
    const float* gzrow = gu_zeros  + ((size_t)e * (2 * I_) + ng) * (H_ / GS_);
    const float* usrow = gu_scales + ((size_t)e * (2 * I_) + nu) * (H_ / GS_);
    const float* uzrow = gu_zeros  + ((size_t)e * (2 * I_) + nu) * (H_ / GS_);

    f32x4 accg[4][2], accu[4][2];
#pragma unroll
    for (int mi = 0; mi < 4; mi++)
#pragma unroll
        for (int ni = 0; ni < 2; ni++) {
            accg[mi][ni] = (f32x4){0.f, 0.f, 0.f, 0.f};
            accu[mi][ni] = (f32x4){0.f, 0.f, 0.f, 0.f};
        }

    s16x8 rX[4];
    int4 rG[2], rU[2];
    float rgs, rgz, rus, ruz;

    // prologue prefetch
    {
        const s16x8* xp = (const s16x8*)(xrow);
        rX[0] = xp[0]; rX[1] = xp[1]; rX[2] = xp[2]; rX[3] = xp[3];
        const int4* gp = (const int4*)(gprow);
        rG[0] = gp[0]; rG[1] = gp[1];
        const int4* up = (const int4*)(uprow);
        rU[0] = up[0]; rU[1] = up[1];
        rgs = gsrow[0]; rgz = gzrow[0]; rus = usrow[0]; ruz = uzrow[0];
    }

    for (int k0 = 0; k0 < H_; k0 += BK) {
        // ---- stage prefetched regs -> LDS ----
        *(s16x8*)&sX[(xr << 6) + CH(xr, xc0 + 0)] = rX[0];
        *(s16x8*)&sX[(xr << 6) + CH(xr, xc0 + 1)] = rX[1];
        *(s16x8*)&sX[(xr << 6) + CH(xr, xc0 + 2)] = rX[2];
        *(s16x8*)&sX[(xr << 6) + CH(xr, xc0 + 3)] = rX[3];
        {
            f16x2 gs2 = {(_Float16)rgs, (_Float16)rgs};
            f16x2 gz2 = {(_Float16)rgz, (_Float16)rgz};
            f16x2 us2 = {(_Float16)rus, (_Float16)rus};
            f16x2 uz2 = {(_Float16)ruz, (_Float16)ruz};
            dq_chunk(rG[0], gs2, gz2, &sG[(wr << 6) + CH(wr, wc0)]);
            dq_chunk(rG[1], gs2, gz2, &sG[(wr << 6) + CH(wr, wc0 + 1)]);
            dq_chunk(rU[0], us2, uz2, &sU[(wr << 6) + CH(wr, wc0)]);
            dq_chunk(rU[1], us2, uz2, &sU[(wr << 6) + CH(wr, wc0 + 1)]);
        }
        __syncthreads();

        // ---- prefetch next K-tile (latency hides behind MFMA below) ----
        if (k0 + BK < H_) {
            const int k1 = k0 + BK;
            const s16x8* xp = (const s16x8*)(xrow + k1);
            rX[0] = xp[0]; rX[1] = xp[1]; rX[2] = xp[2]; rX[3] = xp[3];
            const int4* gp = (const int4*)(gprow + (k1 >> 1));
            rG[0] = gp[0]; rG[1] = gp[1];
            const int4* up = (const int4*)(uprow + (k1 >> 1));
            rU[0] = up[0]; rU[1] = up[1];
            const int g = k1 >> 7;
            rgs = gsrow[g]; rgz = gzrow[g]; rus = usrow[g]; ruz = uzrow[g];
        }

        // ---- MFMA over LDS tiles ----
#pragma unroll
        for (int ks = 0; ks < 2; ks++) {
            const int cb = ks * 4 + quad;
            f16x8 af[4], gf[2], uf[2];
#pragma unroll
            for (int i = 0; i < 4; i++) {
                const int r = wm + i * 16 + l16;
                af[i] = *(const f16x8*)&sX[(r << 6) + CH(r, cb)];
            }
#pragma unroll
            for (int i = 0; i < 2; i++) {
                const int r = wn + i * 16 + l16;
                gf[i] = *(const f16x8*)&sG[(r << 6) + CH(r, cb)];
                uf[i] = *(const f16x8*)&sU[(r << 6) + CH(r, cb)];
            }
#pragma unroll
            for (int mi = 0; mi < 4; mi++)
#pragma unroll
                for (int ni = 0; ni < 2; ni++) {
                    accg[mi][ni] = __builtin_amdgcn_mfma_f32_16x16x32_f16(af[mi], gf[ni], accg[mi][ni], 0, 0, 0);
                    accu[mi][ni] = __builtin_amdgcn_mfma_f32_16x16x32_f16(af[mi], uf[ni], accu[mi][ni], 0, 0, 0);
                }
        }
        __syncthreads();
    }

    // ---- epilogue: gelu(gate)*up -> f16 h ----
#pragma unroll
    for (int mi = 0; mi < 4; mi++) {
#pragma unroll
        for (int rr = 0; rr < 4; rr++) {
            const int row = wm + mi * 16 + quad * 4 + rr;
            const int slot = seg0 + m0 + row;
            if (slot < seg1) {
#pragma unroll
                for (int ni = 0; ni < 2; ni++) {
                    const int col = n0 + wn + ni * 16 + l16;
                    float gv = accg[mi][ni][rr];
                    float uv = accu[mi][ni][rr];
                    float t = tanhf(0.7978845608028654f * (gv + 0.044715f * gv * gv * gv));
                    float hv = 0.5f * gv * (1.0f + t) * uv;
                    h_act[(size_t)slot * I_ + col] = f2h(hv);
                }
            }
        }
    }
}

// ---------------- GEMM2: out[tok] += coef * (h @ Wd^T) ----------------
__global__ __launch_bounds__(256, 5) void gemm2_kernel(
    const unsigned short* __restrict__ h_act,  // [NPAIR][I_] f16 bits
    const int* __restrict__ dn_packed,         // [E][H][I/2] (one byte per int32)
    const float* __restrict__ dn_scales,       // [E][H][I/GS]
    const float* __restrict__ dn_zeros,
    const int* __restrict__ seg,
    const int* __restrict__ ptok,
    const float* __restrict__ pw,
    float* __restrict__ out)                   // [T][H]
{
    const int e = blockIdx.z;
    const int seg0 = seg[e], seg1 = seg[e + 1];
    const int m0 = blockIdx.y * BM;
    if (seg0 + m0 >= seg1) return;
    const int n0 = blockIdx.x * BN;

    __shared__ __align__(16) unsigned short sA[BM * 64];
    __shared__ __align__(16) unsigned short sW[BN * 64];

    const int tid = threadIdx.x;
    const int lane = tid & 63;
    const int wave = tid >> 6;
    const int wm = (wave >> 1) * 64;
    const int wn = (wave & 1) * 32;
    const int quad = lane >> 4;
    const int l16 = lane & 15;

    const int ar = tid >> 1;
    const int ac0 = (tid & 1) * 4;
    int slotA = seg0 + m0 + ar;
    if (slotA > NPAIR - 1) slotA = NPAIR - 1;
    const unsigned short* arow = h_act + (size_t)slotA * I_ + ac0 * 8;

    const int wr = tid >> 2;
    const int wc0 = (tid & 3) * 2;
    const int nw = n0 + wr;
    const int* wprow = dn_packed + ((size_t)e * H_ + nw) * (I_ / 2) + (tid & 3) * 8;
    const float* wsrow = dn_scales + ((size_t)e * H_ + nw) * (I_ / GS_);
    const float* wzrow = dn_zeros  + ((size_t)e * H_ + nw) * (I_ / GS_);

    f32x4 acc[4][2];
#pragma unroll
    for (int mi = 0; mi < 4; mi++)
#pragma unroll
        for (int ni = 0; ni < 2; ni++)
            acc[mi][ni] = (f32x4){0.f, 0.f, 0.f, 0.f};

    s16x8 rA[4];
    int4 rW[2];
    float rs, rz;

    {
        const s16x8* ap = (const s16x8*)(arow);
        rA[0] = ap[0]; rA[1] = ap[1]; rA[2] = ap[2]; rA[3] = ap[3];
        const int4* wp = (const int4*)(wprow);
        rW[0] = wp[0]; rW[1] = wp[1];
        rs = wsrow[0]; rz = wzrow[0];
    }

    for (int k0 = 0; k0 < I_; k0 += BK) {
        *(s16x8*)&sA[(ar << 6) + CH(ar, ac0 + 0)] = rA[0];
        *(s16x8*)&sA[(ar << 6) + CH(ar, ac0 + 1)] = rA[1];
        *(s16x8*)&sA[(ar << 6) + CH(ar, ac0 + 2)] = rA[2];
        *(s16x8*)&sA[(ar << 6) + CH(ar, ac0 + 3)] = rA[3];
        {
            f16x2 ws2 = {(_Float16)rs, (_Float16)rs};
            f16x2 wz2 = {(_Float16)rz, (_Float16)rz};
            dq_chunk(rW[0], ws2, wz2, &sW[(wr << 6) + CH(wr, wc0)]);
            dq_chunk(rW[1], ws2, wz2, &sW[(wr << 6) + CH(wr, wc0 + 1)]);
        }
        __syncthreads();

        if (k0 + BK < I_) {
            const int k1 = k0 + BK;
            const s16x8* ap = (const s16x8*)(arow + k1);
            rA[0] = ap[0]; rA[1] = ap[1]; rA[2] = ap[2]; rA[3] = ap[3];
            const int4* wp = (const int4*)(wprow + (k1 >> 1));
            rW[0] = wp[0]; rW[1] = wp[1];
            const int g = k1 >> 7;
            rs = wsrow[g]; rz = wzrow[g];
        }

#pragma unroll
        for (int ks = 0; ks < 2; ks++) {
            const int cb = ks * 4 + quad;
            f16x8 af[4], wf[2];
#pragma unroll
            for (int i = 0; i < 4; i++) {
                const int r = wm + i * 16 + l16;
                af[i] = *(const f16x8*)&sA[(r << 6) + CH(r, cb)];
            }
#pragma unroll
            for (int i = 0; i < 2; i++) {
                const int r = wn + i * 16 + l16;
                wf[i] = *(const f16x8*)&sW[(r << 6) + CH(r, cb)];
            }
#pragma unroll
            for (int mi = 0; mi < 4; mi++)
#pragma unroll
                for (int ni = 0; ni < 2; ni++)
                    acc[mi][ni] = __builtin_amdgcn_mfma_f32_16x16x32_f16(af[mi], wf[ni], acc[mi][ni], 0, 0, 0);
        }
        __syncthreads();
    }

#pragma unroll
    for (int mi = 0; mi < 4; mi++) {
#pragma unroll
        for (int rr = 0; rr < 4; rr++) {
            const int row = wm + mi * 16 + quad * 4 + rr;
            const int slot = seg0 + m0 + row;
            if (slot < seg1) {
                const int tok = ptok[slot];
                const float cf = pw[slot];
#pragma unroll
                for (int ni = 0; ni < 2; ni++) {
                    const int col = n0 + wn + ni * 16 + l16;
                    atomicAdd(&out[(size_t)tok * H_ + col], cf * acc[mi][ni][rr]);
                }
            }
        }
    }
}

// ---------------- launch ----------------
extern "C" void kernel_launch(void* const* d_in, const int* in_sizes, int n_in,
                              void* d_out, int out_size, void* d_ws, size_t ws_size,
                              hipStream_t stream) {
    const float* x    = (const float*)d_in[0];
    const int*   gu_p = (const int*)d_in[1];     // uint8 in reference -> int32 on device
    const float* gu_s = (const float*)d_in[2];
    const float* gu_z = (const float*)d_in[3];
    const int*   dn_p = (const int*)d_in[4];     // uint8 in reference -> int32 on device
    const float* dn_s = (const float*)d_in[5];
    const float* dn_z = (const float*)d_in[6];
    const int*   ridx = (const int*)d_in[7];
    const float* rw   = (const float*)d_in[8];

    char* ws = (char*)d_ws;
    int*            seg   = (int*)ws;                               // 16 ints
    int*            ptok  = (int*)(ws + 256);                       // 2048 ints
    float*          pw    = (float*)(ws + 256 + NPAIR * 4);         // 2048 floats
    unsigned short* h_act = (unsigned short*)(ws + 32768);          // 16 MB
    unsigned short* xh    = (unsigned short*)(ws + 32768 + (size_t)NPAIR * I_ * 2);  // 4 MB

    float* out = (float*)d_out;

    x2h_kernel<<<T_ * H_ / (256 * 8), 256, 0, stream>>>(x, xh);
    zero_f4<<<(T_ * H_ / 4 + 255) / 256, 256, 0, stream>>>((float4*)out, T_ * H_ / 4);
    router_kernel<<<1, 256, 0, stream>>>(ridx, rw, seg, ptok, pw);
    gemm1_kernel<<<dim3(I_ / BN, NPAIR / BM, E_), 256, 0, stream>>>(
        xh, gu_p, gu_s, gu_z, seg, ptok, h_act);
    gemm2_kernel<<<dim3(H_ / BN, NPAIR / BM, E_), 256, 0, stream>>>(
        h_act, dn_p, dn_s, dn_z, seg, ptok, pw, out);
}

// Round 3
// 969.782 us; speedup vs baseline: 1.6686x; 1.6686x over previous
//
#include <hip/hip_runtime.h>
#include <stdint.h>

// Problem constants (fixed shapes)
#define E_ 8
#define H_ 2048
#define I_ 4096
#define T_ 1024
#define K_ 2
#define GS_ 128
#define NPAIR (T_ * K_)   // 2048

// GEMM tile config
#define BM 128
#define BN 64
#define BK 64

// XOR-swizzled LDS: row stride 64 shorts (128 B), chunk = 8 shorts (16 B).
// chunk c of row r lives at short-offset CH(r,c); conflict-free b128 reads.
#define CH(r, c) ((((c) ^ ((r) & 7)) << 3))

typedef __attribute__((ext_vector_type(8))) short s16x8;    // raw 16B move
typedef _Float16 f16x2 __attribute__((ext_vector_type(2))); // packed half pair
typedef _Float16 f16x8 __attribute__((ext_vector_type(8))); // MFMA A/B frag
typedef __attribute__((ext_vector_type(4))) float f32x4;    // C/D frag

static __device__ __forceinline__ unsigned short f2h(float f) {
    _Float16 h = (_Float16)f;
    return __builtin_bit_cast(unsigned short, h);
}
static __device__ __forceinline__ uint32_t pkrtz(float lo, float hi) {
    return __builtin_bit_cast(uint32_t, __builtin_amdgcn_cvt_pkrtz(lo, hi));
}

// ---------------- x -> f16 pre-pass ----------------
__global__ void x2h_kernel(const float* __restrict__ x, unsigned short* __restrict__ xh) {
    int i = (blockIdx.x * 256 + threadIdx.x) * 8;
    float4 a = *(const float4*)(x + i);
    float4 b = *(const float4*)(x + i + 4);
    uint4 st = make_uint4(pkrtz(a.x, a.y), pkrtz(a.z, a.w),
                          pkrtz(b.x, b.y), pkrtz(b.z, b.w));
    *(uint4*)(xh + i) = st;
}

// ---------------- zero output ----------------
__global__ void zero_f4(float4* p, int n4) {
    int i = blockIdx.x * blockDim.x + threadIdx.x;
    if (i < n4) p[i] = make_float4(0.f, 0.f, 0.f, 0.f);
}

// ---------------- router: build expert-sorted pair list ----------------
__global__ void router_kernel(const int* __restrict__ ridx,
                              const float* __restrict__ rw,
                              int* __restrict__ seg,      // [E_+1]
                              int* __restrict__ ptok,     // [NPAIR]
                              float* __restrict__ pw)     // [NPAIR]
{
    __shared__ int cnt[E_];
    __shared__ int cur[E_];
    int tid = threadIdx.x;
    if (tid < E_) cnt[tid] = 0;
    __syncthreads();
    for (int p = tid; p < NPAIR; p += blockDim.x)
        atomicAdd(&cnt[ridx[p]], 1);
    __syncthreads();
    if (tid == 0) {
        int s = 0;
        for (int e = 0; e < E_; e++) { seg[e] = s; cur[e] = s; s += cnt[e]; }
        seg[E_] = s;
    }
    __syncthreads();
    for (int p = tid; p < NPAIR; p += blockDim.x) {
        int e = ridx[p];
        int pos = atomicAdd(&cur[e], 1);
        ptok[pos] = p >> 1;     // K_ == 2
        pw[pos] = rw[p];
    }
}

// dequant 4 packed bytes (int4 of int32s) -> 8 f16 (one 16B chunk).
// Magic trick: as_half(0x6400 | q) == 1024 + q exactly (q in [0,15]),
// so half2(1024+hi, 1024+lo) is 4 int ops; then (p-1024)*sc+zp in packed
// f16. Subtract 1024 BEFORE the fma: q and 1024+q are exact in f16, while
// folding -1024*sc into the zero point would round at ulp(21) ~ 0.016 and
// poison the weights.
static __device__ __forceinline__ void dq_chunk(int4 q, f16x2 sc, f16x2 zp,
                                                unsigned short* dst) {
    uint32_t r[4];
    int qa[4] = {q.x, q.y, q.z, q.w};
    const f16x2 k1024 = {(_Float16)1024.f, (_Float16)1024.f};
#pragma unroll
    for (int j = 0; j < 4; j++) {
        uint32_t b = (uint32_t)qa[j];          // one meaningful byte per int32
        uint32_t p = 0x64006400u | (b >> 4) | ((b & 0xfu) << 16);
        f16x2 ph = __builtin_bit_cast(f16x2, p);
        f16x2 w = (ph - k1024) * sc + zp;       // v_pk_add + v_pk_fma
        r[j] = __builtin_bit_cast(uint32_t, w);
    }
    *(uint4*)dst = make_uint4(r[0], r[1], r[2], r[3]);
}

// ---------------- GEMM1: h = gelu(x@Wg^T) * (x@Wu^T), f16 out ----------------
__global__ __launch_bounds__(256, 4) void gemm1_kernel(
    const unsigned short* __restrict__ xh,   // [T][H] f16
    const int* __restrict__ gu_packed,       // [E][2I][H/2] (one byte per int32)
    const float* __restrict__ gu_scales,     // [E][2I][H/GS]
    const float* __restrict__ gu_zeros,
    const int* __restrict__ seg,
    const int* __restrict__ ptok,
    unsigned short* __restrict__ h_act)      // [NPAIR][I_] f16 bits
{
    const int e = blockIdx.z;
    const int seg0 = seg[e], seg1 = seg[e + 1];
    const int m0 = blockIdx.y * BM;
    if (seg0 + m0 >= seg1) return;
    const int n0 = blockIdx.x * BN;

    __shared__ __align__(16) unsigned short sX[BM * 64];
    __shared__ __align__(16) unsigned short sG[BN * 64];
    __shared__ __align__(16) unsigned short sU[BN * 64];

    const int tid = threadIdx.x;
    const int lane = tid & 63;
    const int wave = tid >> 6;
    const int wm = (wave >> 1) * 64;   // wave tile 64(m) x 32(n)
    const int wn = (wave & 1) * 32;
    const int quad = lane >> 4;
    const int l16 = lane & 15;

    // X staging: 2 threads/row, 4 chunks (32 shorts) each
    const int xr = tid >> 1;
    const int xc0 = (tid & 1) * 4;
    int slotX = seg0 + m0 + xr;
    if (slotX > NPAIR - 1) slotX = NPAIR - 1;
    const unsigned short* xrow = xh + (size_t)ptok[slotX] * H_ + xc0 * 8;

    // weight staging: 4 threads/row, 8 ints (2 chunks) each
    const int wr = tid >> 2;
    const int wc0 = (tid & 3) * 2;
    const int ng = n0 + wr;
    const int nu = n0 + I_ + wr;
    const int* gprow = gu_packed + ((size_t)e * (2 * I_) + ng) * (H_ / 2) + (tid & 3) * 8;
    const int* uprow = gu_packed + ((size_t)e * (2 * I_) + nu) * (H_ / 2) + (tid & 3) * 8;
    const float* gsrow = gu_scales + ((size_t)e * (2 * I_) + ng) * (H_ / GS_);
    const float* gzrow = gu_zeros  + ((size_t)e * (2 * I_) + ng) * (H_ / GS_);
    const float* usrow = gu_scales + ((size_t)e * (2 * I_) + nu) * (H_ / GS_);
    const float* uzrow = gu_zeros  + ((size_t)e * (2 * I_) + nu) * (H_ / GS_);

    f32x4 accg[4][2], accu[4][2];
#pragma unroll
    for (int mi = 0; mi < 4; mi++)
#pragma unroll
        for (int ni = 0; ni < 2; ni++) {
            accg[mi][ni] = (f32x4){0.f, 0.f, 0.f, 0.f};
            accu[mi][ni] = (f32x4){0.f, 0.f, 0.f, 0.f};
        }

    s16x8 rX[4];
    int4 rG[2], rU[2];
    float rgs, rgz, rus, ruz;

    // prologue prefetch
    {
        const s16x8* xp = (const s16x8*)(xrow);
        rX[0] = xp[0]; rX[1] = xp[1]; rX[2] = xp[2]; rX[3] = xp[3];
        const int4* gp = (const int4*)(gprow);
        rG[0] = gp[0]; rG[1] = gp[1];
        const int4* up = (const int4*)(uprow);
        rU[0] = up[0]; rU[1] = up[1];
        rgs = gsrow[0]; rgz = gzrow[0]; rus = usrow[0]; ruz = uzrow[0];
    }

    for (int k0 = 0; k0 < H_; k0 += BK) {
        // ---- stage prefetched regs -> LDS ----
        *(s16x8*)&sX[(xr << 6) + CH(xr, xc0 + 0)] = rX[0];
        *(s16x8*)&sX[(xr << 6) + CH(xr, xc0 + 1)] = rX[1];
        *(s16x8*)&sX[(xr << 6) + CH(xr, xc0 + 2)] = rX[2];
        *(s16x8*)&sX[(xr << 6) + CH(xr, xc0 + 3)] = rX[3];
        {
            f16x2 gs2 = {(_Float16)rgs, (_Float16)rgs};
            f16x2 gz2 = {(_Float16)rgz, (_Float16)rgz};
            f16x2 us2 = {(_Float16)rus, (_Float16)rus};
            f16x2 uz2 = {(_Float16)ruz, (_Float16)ruz};
            dq_chunk(rG[0], gs2, gz2, &sG[(wr << 6) + CH(wr, wc0)]);
            dq_chunk(rG[1], gs2, gz2, &sG[(wr << 6) + CH(wr, wc0 + 1)]);
            dq_chunk(rU[0], us2, uz2, &sU[(wr << 6) + CH(wr, wc0)]);
            dq_chunk(rU[1], us2, uz2, &sU[(wr << 6) + CH(wr, wc0 + 1)]);
        }
        __syncthreads();

        // ---- prefetch next K-tile (latency hides behind MFMA below) ----
        if (k0 + BK < H_) {
            const int k1 = k0 + BK;
            const s16x8* xp = (const s16x8*)(xrow + k1);
            rX[0] = xp[0]; rX[1] = xp[1]; rX[2] = xp[2]; rX[3] = xp[3];
            const int4* gp = (const int4*)(gprow + (k1 >> 1));
            rG[0] = gp[0]; rG[1] = gp[1];
            const int4* up = (const int4*)(uprow + (k1 >> 1));
            rU[0] = up[0]; rU[1] = up[1];
            const int g = k1 >> 7;
            rgs = gsrow[g]; rgz = gzrow[g]; rus = usrow[g]; ruz = uzrow[g];
        }

        // ---- MFMA over LDS tiles ----
#pragma unroll
        for (int ks = 0; ks < 2; ks++) {
            const int cb = ks * 4 + quad;
            f16x8 af[4], gf[2], uf[2];
#pragma unroll
            for (int i = 0; i < 4; i++) {
                const int r = wm + i * 16 + l16;
                af[i] = *(const f16x8*)&sX[(r << 6) + CH(r, cb)];
            }
#pragma unroll
            for (int i = 0; i < 2; i++) {
                const int r = wn + i * 16 + l16;
                gf[i] = *(const f16x8*)&sG[(r << 6) + CH(r, cb)];
                uf[i] = *(const f16x8*)&sU[(r << 6) + CH(r, cb)];
            }
#pragma unroll
            for (int mi = 0; mi < 4; mi++)
#pragma unroll
                for (int ni = 0; ni < 2; ni++) {
                    accg[mi][ni] = __builtin_amdgcn_mfma_f32_16x16x32_f16(af[mi], gf[ni], accg[mi][ni], 0, 0, 0);
                    accu[mi][ni] = __builtin_amdgcn_mfma_f32_16x16x32_f16(af[mi], uf[ni], accu[mi][ni], 0, 0, 0);
                }
        }
        __syncthreads();
    }

    // ---- epilogue: gelu(gate)*up -> f16 h ----
#pragma unroll
    for (int mi = 0; mi < 4; mi++) {
#pragma unroll
        for (int rr = 0; rr < 4; rr++) {
            const int row = wm + mi * 16 + quad * 4 + rr;
            const int slot = seg0 + m0 + row;
            if (slot < seg1) {
#pragma unroll
                for (int ni = 0; ni < 2; ni++) {
                    const int col = n0 + wn + ni * 16 + l16;
                    float gv = accg[mi][ni][rr];
                    float uv = accu[mi][ni][rr];
                    float t = tanhf(0.7978845608028654f * (gv + 0.044715f * gv * gv * gv));
                    float hv = 0.5f * gv * (1.0f + t) * uv;
                    h_act[(size_t)slot * I_ + col] = f2h(hv);
                }
            }
        }
    }
}

// ---------------- GEMM2: out[tok] += coef * (h @ Wd^T) ----------------
__global__ __launch_bounds__(256, 4) void gemm2_kernel(
    const unsigned short* __restrict__ h_act,  // [NPAIR][I_] f16 bits
    const int* __restrict__ dn_packed,         // [E][H][I/2] (one byte per int32)
    const float* __restrict__ dn_scales,       // [E][H][I/GS]
    const float* __restrict__ dn_zeros,
    const int* __restrict__ seg,
    const int* __restrict__ ptok,
    const float* __restrict__ pw,
    float* __restrict__ out)                   // [T][H]
{
    const int e = blockIdx.z;
    const int seg0 = seg[e], seg1 = seg[e + 1];
    const int m0 = blockIdx.y * BM;
    if (seg0 + m0 >= seg1) return;
    const int n0 = blockIdx.x * BN;

    __shared__ __align__(16) unsigned short sA[BM * 64];
    __shared__ __align__(16) unsigned short sW[BN * 64];

    const int tid = threadIdx.x;
    const int lane = tid & 63;
    const int wave = tid >> 6;
    const int wm = (wave >> 1) * 64;
    const int wn = (wave & 1) * 32;
    const int quad = lane >> 4;
    const int l16 = lane & 15;

    const int ar = tid >> 1;
    const int ac0 = (tid & 1) * 4;
    int slotA = seg0 + m0 + ar;
    if (slotA > NPAIR - 1) slotA = NPAIR - 1;
    const unsigned short* arow = h_act + (size_t)slotA * I_ + ac0 * 8;

    const int wr = tid >> 2;
    const int wc0 = (tid & 3) * 2;
    const int nw = n0 + wr;
    const int* wprow = dn_packed + ((size_t)e * H_ + nw) * (I_ / 2) + (tid & 3) * 8;
    const float* wsrow = dn_scales + ((size_t)e * H_ + nw) * (I_ / GS_);
    const float* wzrow = dn_zeros  + ((size_t)e * H_ + nw) * (I_ / GS_);

    f32x4 acc[4][2];
#pragma unroll
    for (int mi = 0; mi < 4; mi++)
#pragma unroll
        for (int ni = 0; ni < 2; ni++)
            acc[mi][ni] = (f32x4){0.f, 0.f, 0.f, 0.f};

    s16x8 rA[4];
    int4 rW[2];
    float rs, rz;

    {
        const s16x8* ap = (const s16x8*)(arow);
        rA[0] = ap[0]; rA[1] = ap[1]; rA[2] = ap[2]; rA[3] = ap[3];
        const int4* wp = (const int4*)(wprow);
        rW[0] = wp[0]; rW[1] = wp[1];
        rs = wsrow[0]; rz = wzrow[0];
    }

    for (int k0 = 0; k0 < I_; k0 += BK) {
        *(s16x8*)&sA[(ar << 6) + CH(ar, ac0 + 0)] = rA[0];
        *(s16x8*)&sA[(ar << 6) + CH(ar, ac0 + 1)] = rA[1];
        *(s16x8*)&sA[(ar << 6) + CH(ar, ac0 + 2)] = rA[2];
        *(s16x8*)&sA[(ar << 6) + CH(ar, ac0 + 3)] = rA[3];
        {
            f16x2 ws2 = {(_Float16)rs, (_Float16)rs};
            f16x2 wz2 = {(_Float16)rz, (_Float16)rz};
            dq_chunk(rW[0], ws2, wz2, &sW[(wr << 6) + CH(wr, wc0)]);
            dq_chunk(rW[1], ws2, wz2, &sW[(wr << 6) + CH(wr, wc0 + 1)]);
        }
        __syncthreads();

        if (k0 + BK < I_) {
            const int k1 = k0 + BK;
            const s16x8* ap = (const s16x8*)(arow + k1);
            rA[0] = ap[0]; rA[1] = ap[1]; rA[2] = ap[2]; rA[3] = ap[3];
            const int4* wp = (const int4*)(wprow + (k1 >> 1));
            rW[0] = wp[0]; rW[1] = wp[1];
            const int g = k1 >> 7;
            rs = wsrow[g]; rz = wzrow[g];
        }

#pragma unroll
        for (int ks = 0; ks < 2; ks++) {
            const int cb = ks * 4 + quad;
            f16x8 af[4], wf[2];
#pragma unroll
            for (int i = 0; i < 4; i++) {
                const int r = wm + i * 16 + l16;
                af[i] = *(const f16x8*)&sA[(r << 6) + CH(r, cb)];
            }
#pragma unroll
            for (int i = 0; i < 2; i++) {
                const int r = wn + i * 16 + l16;
                wf[i] = *(const f16x8*)&sW[(r << 6) + CH(r, cb)];
            }
#pragma unroll
            for (int mi = 0; mi < 4; mi++)
#pragma unroll
                for (int ni = 0; ni < 2; ni++)
                    acc[mi][ni] = __builtin_amdgcn_mfma_f32_16x16x32_f16(af[mi], wf[ni], acc[mi][ni], 0, 0, 0);
        }
        __syncthreads();
    }

#pragma unroll
    for (int mi = 0; mi < 4; mi++) {
#pragma unroll
        for (int rr = 0; rr < 4; rr++) {
            const int row = wm + mi * 16 + quad * 4 + rr;
            const int slot = seg0 + m0 + row;
            if (slot < seg1) {
                const int tok = ptok[slot];
                const float cf = pw[slot];
#pragma unroll
                for (int ni = 0; ni < 2; ni++) {
                    const int col = n0 + wn + ni * 16 + l16;
                    atomicAdd(&out[(size_t)tok * H_ + col], cf * acc[mi][ni][rr]);
                }
            }
        }
    }
}

// ---------------- launch ----------------
extern "C" void kernel_launch(void* const* d_in, const int* in_sizes, int n_in,
                              void* d_out, int out_size, void* d_ws, size_t ws_size,
                              hipStream_t stream) {
    const float* x    = (const float*)d_in[0];
    const int*   gu_p = (const int*)d_in[1];     // uint8 in reference -> int32 on device
    const float* gu_s = (const float*)d_in[2];
    const float* gu_z = (const float*)d_in[3];
    const int*   dn_p = (const int*)d_in[4];     // uint8 in reference -> int32 on device
    const float* dn_s = (const float*)d_in[5];
    const float* dn_z = (const float*)d_in[6];
    const int*   ridx = (const int*)d_in[7];
    const float* rw   = (const float*)d_in[8];

    char* ws = (char*)d_ws;
    int*            seg   = (int*)ws;                               // 16 ints
    int*            ptok  = (int*)(ws + 256);                       // 2048 ints
    float*          pw    = (float*)(ws + 256 + NPAIR * 4);         // 2048 floats
    unsigned short* h_act = (unsigned short*)(ws + 32768);          // 16 MB
    unsigned short* xh    = (unsigned short*)(ws + 32768 + (size_t)NPAIR * I_ * 2);  // 4 MB

    float* out = (float*)d_out;

    x2h_kernel<<<T_ * H_ / (256 * 8), 256, 0, stream>>>(x, xh);
    zero_f4<<<(T_ * H_ / 4 + 255) / 256, 256, 0, stream>>>((float4*)out, T_ * H_ / 4);
    router_kernel<<<1, 256, 0, stream>>>(ridx, rw, seg, ptok, pw);
    gemm1_kernel<<<dim3(I_ / BN, NPAIR / BM, E_), 256, 0, stream>>>(
        xh, gu_p, gu_s, gu_z, seg, ptok, h_act);
    gemm2_kernel<<<dim3(H_ / BN, NPAIR / BM, E_), 256, 0, stream>>>(
        h_act, dn_p, dn_s, dn_z, seg, ptok, pw, out);
}

// Round 4
// 680.784 us; speedup vs baseline: 2.3770x; 1.4245x over previous
//
#include <hip/hip_runtime.h>
#include <stdint.h>

// Problem constants (fixed shapes)
#define E_ 8
#define H_ 2048
#define I_ 4096
#define T_ 1024
#define K_ 2
#define GS_ 128
#define NPAIR (T_ * K_)   // 2048

// GEMM tile config
#define BM 128
#define BN 64
#define BK 64

// XOR-swizzled LDS: row stride 64 shorts (128 B), chunk = 8 shorts (16 B).
// chunk c of row r lives at short-offset CH(r,c); conflict-free b128 reads.
#define CH(r, c) ((((c) ^ ((r) & 7)) << 3))

typedef __attribute__((ext_vector_type(8))) short s16x8;    // raw 16B move
typedef _Float16 f16x2 __attribute__((ext_vector_type(2))); // packed half pair
typedef _Float16 f16x8 __attribute__((ext_vector_type(8))); // MFMA A/B frag
typedef __attribute__((ext_vector_type(4))) float f32x4;    // C/D frag

static __device__ __forceinline__ unsigned short f2h(float f) {
    _Float16 h = (_Float16)f;
    return __builtin_bit_cast(unsigned short, h);
}
static __device__ __forceinline__ uint32_t pkrtz(float lo, float hi) {
    return __builtin_bit_cast(uint32_t, __builtin_amdgcn_cvt_pkrtz(lo, hi));
}

// ---------------- x -> f16 pre-pass ----------------
__global__ void x2h_kernel(const float* __restrict__ x, unsigned short* __restrict__ xh) {
    int i = (blockIdx.x * 256 + threadIdx.x) * 8;
    float4 a = *(const float4*)(x + i);
    float4 b = *(const float4*)(x + i + 4);
    uint4 st = make_uint4(pkrtz(a.x, a.y), pkrtz(a.z, a.w),
                          pkrtz(b.x, b.y), pkrtz(b.z, b.w));
    *(uint4*)(xh + i) = st;
}

// ---------------- zero output ----------------
__global__ void zero_f4(float4* p, int n4) {
    int i = blockIdx.x * blockDim.x + threadIdx.x;
    if (i < n4) p[i] = make_float4(0.f, 0.f, 0.f, 0.f);
}

// ---------------- router: build expert-sorted pair list ----------------
__global__ void router_kernel(const int* __restrict__ ridx,
                              const float* __restrict__ rw,
                              int* __restrict__ seg,      // [E_+1]
                              int* __restrict__ ptok,     // [NPAIR]
                              float* __restrict__ pw)     // [NPAIR]
{
    __shared__ int cnt[E_];
    __shared__ int cur[E_];
    int tid = threadIdx.x;
    if (tid < E_) cnt[tid] = 0;
    __syncthreads();
    for (int p = tid; p < NPAIR; p += blockDim.x)
        atomicAdd(&cnt[ridx[p]], 1);
    __syncthreads();
    if (tid == 0) {
        int s = 0;
        for (int e = 0; e < E_; e++) { seg[e] = s; cur[e] = s; s += cnt[e]; }
        seg[E_] = s;
    }
    __syncthreads();
    for (int p = tid; p < NPAIR; p += blockDim.x) {
        int e = ridx[p];
        int pos = atomicAdd(&cur[e], 1);
        ptok[pos] = p >> 1;     // K_ == 2
        pw[pos] = rw[p];
    }
}

// dequant 4 packed bytes (int4 of int32s) -> 8 f16 (one 16B chunk).
// Magic trick: as_half(0x6400 | q) == 1024 + q exactly (q in [0,15]),
// so half2(1024+hi, 1024+lo) is 4 int ops; then (p-1024)*sc+zp in packed
// f16. Subtract 1024 BEFORE the fma: q and 1024+q are exact in f16, while
// folding -1024*sc into the zero point would round at ulp(21) ~ 0.016 and
// poison the weights.
static __device__ __forceinline__ void dq_chunk(int4 q, f16x2 sc, f16x2 zp,
                                                unsigned short* dst) {
    uint32_t r[4];
    int qa[4] = {q.x, q.y, q.z, q.w};
    const f16x2 k1024 = {(_Float16)1024.f, (_Float16)1024.f};
#pragma unroll
    for (int j = 0; j < 4; j++) {
        uint32_t b = (uint32_t)qa[j];          // one meaningful byte per int32
        uint32_t p = 0x64006400u | (b >> 4) | ((b & 0xfu) << 16);
        f16x2 ph = __builtin_bit_cast(f16x2, p);
        f16x2 w = (ph - k1024) * sc + zp;       // v_pk_add + v_pk_fma
        r[j] = __builtin_bit_cast(uint32_t, w);
    }
    *(uint4*)dst = make_uint4(r[0], r[1], r[2], r[3]);
}

// ---------------- GEMM1: h = gelu(x@Wg^T) * (x@Wu^T), f16 out ----------------
__global__ __launch_bounds__(256, 3) void gemm1_kernel(
    const unsigned short* __restrict__ xh,   // [T][H] f16
    const int* __restrict__ gu_packed,       // [E][2I][H/2] (one byte per int32)
    const float* __restrict__ gu_scales,     // [E][2I][H/GS]
    const float* __restrict__ gu_zeros,
    const int* __restrict__ seg,
    const int* __restrict__ ptok,
    unsigned short* __restrict__ h_act)      // [NPAIR][I_] f16 bits
{
    const int e = blockIdx.z;
    const int seg0 = seg[e], seg1 = seg[e + 1];
    const int m0 = blockIdx.y * BM;
    if (seg0 + m0 >= seg1) return;
    const int n0 = blockIdx.x * BN;

    __shared__ __align__(16) unsigned short sX[BM * 64];
    __shared__ __align__(16) unsigned short sG[BN * 64];
    __shared__ __align__(16) unsigned short sU[BN * 64];

    const int tid = threadIdx.x;
    const int lane = tid & 63;
    const int wave = tid >> 6;
    const int wm = (wave >> 1) * 64;   // wave tile 64(m) x 32(n)
    const int wn = (wave & 1) * 32;
    const int quad = lane >> 4;
    const int l16 = lane & 15;

    // X staging: 2 threads/row, 4 chunks (32 shorts) each
    const int xr = tid >> 1;
    const int xc0 = (tid & 1) * 4;
    int slotX = seg0 + m0 + xr;
    if (slotX > NPAIR - 1) slotX = NPAIR - 1;
    const unsigned short* xrow = xh + (size_t)ptok[slotX] * H_ + xc0 * 8;

    // weight staging: 4 threads/row, 8 ints (2 chunks) each
    const int wr = tid >> 2;
    const int wc0 = (tid & 3) * 2;
    const int ng = n0 + wr;
    const int nu = n0 + I_ + wr;
    const int* gprow = gu_packed + ((size_t)e * (2 * I_) + ng) * (H_ / 2) + (tid & 3) * 8;
    const int* uprow = gu_packed + ((size_t)e * (2 * I_) + nu) * (H_ / 2) + (tid & 3) * 8;
    const float* gsrow = gu_scales + ((size_t)e * (2 * I_) + ng) * (H_ / GS_);
    const float* gzrow = gu_zeros  + ((size_t)e * (2 * I_) + ng) * (H_ / GS_);
    const float* usrow = gu_scales + ((size_t)e * (2 * I_) + nu) * (H_ / GS_);
    const float* uzrow = gu_zeros  + ((size_t)e * (2 * I_) + nu) * (H_ / GS_);

    f32x4 accg[4][2], accu[4][2];
#pragma unroll
    for (int mi = 0; mi < 4; mi++)
#pragma unroll
        for (int ni = 0; ni < 2; ni++) {
            accg[mi][ni] = (f32x4){0.f, 0.f, 0.f, 0.f};
            accu[mi][ni] = (f32x4){0.f, 0.f, 0.f, 0.f};
        }

    s16x8 rX[4];
    int4 rG[2], rU[2];
    float rgs, rgz, rus, ruz;

    // prologue prefetch
    {
        const s16x8* xp = (const s16x8*)(xrow);
        rX[0] = xp[0]; rX[1] = xp[1]; rX[2] = xp[2]; rX[3] = xp[3];
        const int4* gp = (const int4*)(gprow);
        rG[0] = gp[0]; rG[1] = gp[1];
        const int4* up = (const int4*)(uprow);
        rU[0] = up[0]; rU[1] = up[1];
        rgs = gsrow[0]; rgz = gzrow[0]; rus = usrow[0]; ruz = uzrow[0];
    }

    for (int k0 = 0; k0 < H_; k0 += BK) {
        // ---- stage prefetched regs -> LDS ----
        *(s16x8*)&sX[(xr << 6) + CH(xr, xc0 + 0)] = rX[0];
        *(s16x8*)&sX[(xr << 6) + CH(xr, xc0 + 1)] = rX[1];
        *(s16x8*)&sX[(xr << 6) + CH(xr, xc0 + 2)] = rX[2];
        *(s16x8*)&sX[(xr << 6) + CH(xr, xc0 + 3)] = rX[3];
        {
            f16x2 gs2 = {(_Float16)rgs, (_Float16)rgs};
            f16x2 gz2 = {(_Float16)rgz, (_Float16)rgz};
            f16x2 us2 = {(_Float16)rus, (_Float16)rus};
            f16x2 uz2 = {(_Float16)ruz, (_Float16)ruz};
            dq_chunk(rG[0], gs2, gz2, &sG[(wr << 6) + CH(wr, wc0)]);
            dq_chunk(rG[1], gs2, gz2, &sG[(wr << 6) + CH(wr, wc0 + 1)]);
            dq_chunk(rU[0], us2, uz2, &sU[(wr << 6) + CH(wr, wc0)]);
            dq_chunk(rU[1], us2, uz2, &sU[(wr << 6) + CH(wr, wc0 + 1)]);
        }
        __syncthreads();

        // ---- prefetch next K-tile (latency hides behind MFMA below) ----
        if (k0 + BK < H_) {
            const int k1 = k0 + BK;
            const s16x8* xp = (const s16x8*)(xrow + k1);
            rX[0] = xp[0]; rX[1] = xp[1]; rX[2] = xp[2]; rX[3] = xp[3];
            const int4* gp = (const int4*)(gprow + (k1 >> 1));
            rG[0] = gp[0]; rG[1] = gp[1];
            const int4* up = (const int4*)(uprow + (k1 >> 1));
            rU[0] = up[0]; rU[1] = up[1];
            const int g = k1 >> 7;
            rgs = gsrow[g]; rgz = gzrow[g]; rus = usrow[g]; ruz = uzrow[g];
        }

        // ---- MFMA over LDS tiles ----
#pragma unroll
        for (int ks = 0; ks < 2; ks++) {
            const int cb = ks * 4 + quad;
            f16x8 af[4], gf[2], uf[2];
#pragma unroll
            for (int i = 0; i < 4; i++) {
                const int r = wm + i * 16 + l16;
                af[i] = *(const f16x8*)&sX[(r << 6) + CH(r, cb)];
            }
#pragma unroll
            for (int i = 0; i < 2; i++) {
                const int r = wn + i * 16 + l16;
                gf[i] = *(const f16x8*)&sG[(r << 6) + CH(r, cb)];
                uf[i] = *(const f16x8*)&sU[(r << 6) + CH(r, cb)];
            }
#pragma unroll
            for (int mi = 0; mi < 4; mi++)
#pragma unroll
                for (int ni = 0; ni < 2; ni++) {
                    accg[mi][ni] = __builtin_amdgcn_mfma_f32_16x16x32_f16(af[mi], gf[ni], accg[mi][ni], 0, 0, 0);
                    accu[mi][ni] = __builtin_amdgcn_mfma_f32_16x16x32_f16(af[mi], uf[ni], accu[mi][ni], 0, 0, 0);
                }
        }
        __syncthreads();
    }

    // ---- epilogue: gelu(gate)*up -> f16 h ----
#pragma unroll
    for (int mi = 0; mi < 4; mi++) {
#pragma unroll
        for (int rr = 0; rr < 4; rr++) {
            const int row = wm + mi * 16 + quad * 4 + rr;
            const int slot = seg0 + m0 + row;
            if (slot < seg1) {
#pragma unroll
                for (int ni = 0; ni < 2; ni++) {
                    const int col = n0 + wn + ni * 16 + l16;
                    float gv = accg[mi][ni][rr];
                    float uv = accu[mi][ni][rr];
                    float t = tanhf(0.7978845608028654f * (gv + 0.044715f * gv * gv * gv));
                    float hv = 0.5f * gv * (1.0f + t) * uv;
                    h_act[(size_t)slot * I_ + col] = f2h(hv);
                }
            }
        }
    }
}

// ---------------- GEMM2: out[tok] += coef * (h @ Wd^T) ----------------
__global__ __launch_bounds__(256, 3) void gemm2_kernel(
    const unsigned short* __restrict__ h_act,  // [NPAIR][I_] f16 bits
    const int* __restrict__ dn_packed,         // [E][H][I/2] (one byte per int32)
    const float* __restrict__ dn_scales,       // [E][H][I/GS]
    const float* __restrict__ dn_zeros,
    const int* __restrict__ seg,
    const int* __restrict__ ptok,
    const float* __restrict__ pw,
    float* __restrict__ out)                   // [T][H]
{
    const int e = blockIdx.z;
    const int seg0 = seg[e], seg1 = seg[e + 1];
    const int m0 = blockIdx.y * BM;
    if (seg0 + m0 >= seg1) return;
    const int n0 = blockIdx.x * BN;

    __shared__ __align__(16) unsigned short sA[BM * 64];
    __shared__ __align__(16) unsigned short sW[BN * 64];

    const int tid = threadIdx.x;
    const int lane = tid & 63;
    const int wave = tid >> 6;
    const int wm = (wave >> 1) * 64;
    const int wn = (wave & 1) * 32;
    const int quad = lane >> 4;
    const int l16 = lane & 15;

    const int ar = tid >> 1;
    const int ac0 = (tid & 1) * 4;
    int slotA = seg0 + m0 + ar;
    if (slotA > NPAIR - 1) slotA = NPAIR - 1;
    const unsigned short* arow = h_act + (size_t)slotA * I_ + ac0 * 8;

    const int wr = tid >> 2;
    const int wc0 = (tid & 3) * 2;
    const int nw = n0 + wr;
    const int* wprow = dn_packed + ((size_t)e * H_ + nw) * (I_ / 2) + (tid & 3) * 8;
    const float* wsrow = dn_scales + ((size_t)e * H_ + nw) * (I_ / GS_);
    const float* wzrow = dn_zeros  + ((size_t)e * H_ + nw) * (I_ / GS_);

    f32x4 acc[4][2];
#pragma unroll
    for (int mi = 0; mi < 4; mi++)
#pragma unroll
        for (int ni = 0; ni < 2; ni++)
            acc[mi][ni] = (f32x4){0.f, 0.f, 0.f, 0.f};

    s16x8 rA[4];
    int4 rW[2];
    float rs, rz;

    {
        const s16x8* ap = (const s16x8*)(arow);
        rA[0] = ap[0]; rA[1] = ap[1]; rA[2] = ap[2]; rA[3] = ap[3];
        const int4* wp = (const int4*)(wprow);
        rW[0] = wp[0]; rW[1] = wp[1];
        rs = wsrow[0]; rz = wzrow[0];
    }

    for (int k0 = 0; k0 < I_; k0 += BK) {
        *(s16x8*)&sA[(ar << 6) + CH(ar, ac0 + 0)] = rA[0];
        *(s16x8*)&sA[(ar << 6) + CH(ar, ac0 + 1)] = rA[1];
        *(s16x8*)&sA[(ar << 6) + CH(ar, ac0 + 2)] = rA[2];
        *(s16x8*)&sA[(ar << 6) + CH(ar, ac0 + 3)] = rA[3];
        {
            f16x2 ws2 = {(_Float16)rs, (_Float16)rs};
            f16x2 wz2 = {(_Float16)rz, (_Float16)rz};
            dq_chunk(rW[0], ws2, wz2, &sW[(wr << 6) + CH(wr, wc0)]);
            dq_chunk(rW[1], ws2, wz2, &sW[(wr << 6) + CH(wr, wc0 + 1)]);
        }
        __syncthreads();

        if (k0 + BK < I_) {
            const int k1 = k0 + BK;
            const s16x8* ap = (const s16x8*)(arow + k1);
            rA[0] = ap[0]; rA[1] = ap[1]; rA[2] = ap[2]; rA[3] = ap[3];
            const int4* wp = (const int4*)(wprow + (k1 >> 1));
            rW[0] = wp[0]; rW[1] = wp[1];
            const int g = k1 >> 7;
            rs = wsrow[g]; rz = wzrow[g];
        }

#pragma unroll
        for (int ks = 0; ks < 2; ks++) {
            const int cb = ks * 4 + quad;
            f16x8 af[4], wf[2];
#pragma unroll
            for (int i = 0; i < 4; i++) {
                const int r = wm + i * 16 + l16;
                af[i] = *(const f16x8*)&sA[(r << 6) + CH(r, cb)];
            }
#pragma unroll
            for (int i = 0; i < 2; i++) {
                const int r = wn + i * 16 + l16;
                wf[i] = *(const f16x8*)&sW[(r << 6) + CH(r, cb)];
            }
#pragma unroll
            for (int mi = 0; mi < 4; mi++)
#pragma unroll
                for (int ni = 0; ni < 2; ni++)
                    acc[mi][ni] = __builtin_amdgcn_mfma_f32_16x16x32_f16(af[mi], wf[ni], acc[mi][ni], 0, 0, 0);
        }
        __syncthreads();
    }

#pragma unroll
    for (int mi = 0; mi < 4; mi++) {
#pragma unroll
        for (int rr = 0; rr < 4; rr++) {
            const int row = wm + mi * 16 + quad * 4 + rr;
            const int slot = seg0 + m0 + row;
            if (slot < seg1) {
                const int tok = ptok[slot];
                const float cf = pw[slot];
#pragma unroll
                for (int ni = 0; ni < 2; ni++) {
                    const int col = n0 + wn + ni * 16 + l16;
                    atomicAdd(&out[(size_t)tok * H_ + col], cf * acc[mi][ni][rr]);
                }
            }
        }
    }
}

// ---------------- launch ----------------
extern "C" void kernel_launch(void* const* d_in, const int* in_sizes, int n_in,
                              void* d_out, int out_size, void* d_ws, size_t ws_size,
                              hipStream_t stream) {
    const float* x    = (const float*)d_in[0];
    const int*   gu_p = (const int*)d_in[1];     // uint8 in reference -> int32 on device
    const float* gu_s = (const float*)d_in[2];
    const float* gu_z = (const float*)d_in[3];
    const int*   dn_p = (const int*)d_in[4];     // uint8 in reference -> int32 on device
    const float* dn_s = (const float*)d_in[5];
    const float* dn_z = (const float*)d_in[6];
    const int*   ridx = (const int*)d_in[7];
    const float* rw   = (const float*)d_in[8];

    char* ws = (char*)d_ws;
    int*            seg   = (int*)ws;                               // 16 ints
    int*            ptok  = (int*)(ws + 256);                       // 2048 ints
    float*          pw    = (float*)(ws + 256 + NPAIR * 4);         // 2048 floats
    unsigned short* h_act = (unsigned short*)(ws + 32768);          // 16 MB
    unsigned short* xh    = (unsigned short*)(ws + 32768 + (size_t)NPAIR * I_ * 2);  // 4 MB

    float* out = (float*)d_out;

    x2h_kernel<<<T_ * H_ / (256 * 8), 256, 0, stream>>>(x, xh);
    zero_f4<<<(T_ * H_ / 4 + 255) / 256, 256, 0, stream>>>((float4*)out, T_ * H_ / 4);
    router_kernel<<<1, 256, 0, stream>>>(ridx, rw, seg, ptok, pw);
    gemm1_kernel<<<dim3(I_ / BN, NPAIR / BM, E_), 256, 0, stream>>>(
        xh, gu_p, gu_s, gu_z, seg, ptok, h_act);
    gemm2_kernel<<<dim3(H_ / BN, NPAIR / BM, E_), 256, 0, stream>>>(
        h_act, dn_p, dn_s, dn_z, seg, ptok, pw, out);
}